// Round 1
// baseline (83.615 us; speedup 1.0000x reference)
//
#include <hip/hip_runtime.h>

// SPQR dequant-GEMV: y[b][m] = sum_n x[b][n] * Wd[m][n] + CSR outlier correction
// M=N=8192, beta1=beta2=16, B(=b*l)=10, 32 nnz/row.

constexpr int M_DIM = 8192;
constexpr int N_DIM = 8192;
constexpr int TN    = 512;          // N / 16
constexpr int BQ    = 10;           // batch (b*l)
constexpr int RB    = 4;            // rows per block
constexpr int NTHREADS = 256;
constexpr int NC    = NTHREADS * 4; // 1024 columns per chunk
constexpr int NCHUNK = N_DIM / NC;  // 8

__global__ __launch_bounds__(NTHREADS, 4)
void spqr_fused(const float* __restrict__ x,
                const int*   __restrict__ W,
                const int*   __restrict__ Ws,
                const int*   __restrict__ Wz,
                const float* __restrict__ Wss,
                const float* __restrict__ Wsz,
                const float* __restrict__ Wzs,
                const float* __restrict__ Wzz,
                const int*   __restrict__ row_offsets,
                const int*   __restrict__ col_ids,
                const float* __restrict__ values,
                float*       __restrict__ y)
{
    const int t  = threadIdx.x;
    const int m0 = blockIdx.x * RB;

    float acc[RB][BQ];
    #pragma unroll
    for (int r = 0; r < RB; ++r)
        #pragma unroll
        for (int b = 0; b < BQ; ++b)
            acc[r][b] = 0.f;

    for (int chunk = 0; chunk < NCHUNK; ++chunk) {
        const int n0 = chunk * NC + t * 4;   // this thread's 4 columns
        // x[b][n0..n0+3] -> registers (coalesced float4, L2-resident)
        float4 xv[BQ];
        #pragma unroll
        for (int b = 0; b < BQ; ++b)
            xv[b] = *reinterpret_cast<const float4*>(x + b * N_DIM + n0);

        const int g = n0 >> 4;               // scale-group index (all 4 cols in same group)

        #pragma unroll
        for (int r = 0; r < RB; ++r) {
            const int m  = m0 + r;
            const int ti = m >> 4;
            const int tIdx = ti * TN + g;
            // two-level dequant of scale & zero
            const float s = ((float)Ws[m * TN + g] - Wsz[tIdx]) * Wss[tIdx];
            const float z = ((float)Wz[m * TN + g] - Wzz[tIdx]) * Wzs[tIdx];
            // 4 weight codes, coalesced 16B load
            const int4 wc = *reinterpret_cast<const int4*>(W + (size_t)m * N_DIM + n0);
            const float w0 = ((float)wc.x - z) * s;
            const float w1 = ((float)wc.y - z) * s;
            const float w2 = ((float)wc.z - z) * s;
            const float w3 = ((float)wc.w - z) * s;
            #pragma unroll
            for (int b = 0; b < BQ; ++b) {
                float a = acc[r][b];
                a = fmaf(w0, xv[b].x, a);
                a = fmaf(w1, xv[b].y, a);
                a = fmaf(w2, xv[b].z, a);
                a = fmaf(w3, xv[b].w, a);
                acc[r][b] = a;
            }
        }
    }

    // ---- wave-level reduction of the 40 partials across 64 lanes ----
    #pragma unroll
    for (int r = 0; r < RB; ++r)
        #pragma unroll
        for (int b = 0; b < BQ; ++b) {
            float v = acc[r][b];
            for (int off = 32; off > 0; off >>= 1)
                v += __shfl_xor(v, off, 64);
            acc[r][b] = v;
        }

    __shared__ float lds_part[NTHREADS / 64][RB * BQ];
    __shared__ float lds_sp[RB][BQ];

    const int wave = t >> 6;
    const int lane = t & 63;
    if (lane == 0) {
        #pragma unroll
        for (int r = 0; r < RB; ++r)
            #pragma unroll
            for (int b = 0; b < BQ; ++b)
                lds_part[wave][r * BQ + b] = acc[r][b];
    }
    if (t < RB * BQ)
        lds_sp[t / BQ][t % BQ] = 0.f;
    __syncthreads();

    // ---- fused CSR outlier correction: 32 lanes per row ----
    if (t < RB * 32) {
        const int r = t >> 5;
        const int j = t & 31;
        const int m = m0 + r;
        const int base = row_offsets[m];
        const int cnt  = row_offsets[m + 1] - base;
        float c[BQ];
        #pragma unroll
        for (int b = 0; b < BQ; ++b) c[b] = 0.f;
        for (int jj = j; jj < cnt; jj += 32) {
            const int   col = col_ids[base + jj];
            const float v   = values[base + jj];
            #pragma unroll
            for (int b = 0; b < BQ; ++b)
                c[b] = fmaf(v, x[b * N_DIM + col], c[b]);
        }
        #pragma unroll
        for (int b = 0; b < BQ; ++b) {
            float v = c[b];
            for (int off = 16; off > 0; off >>= 1)
                v += __shfl_xor(v, off, 32);
            c[b] = v;
        }
        if (j == 0) {
            #pragma unroll
            for (int b = 0; b < BQ; ++b)
                lds_sp[r][b] = c[b];
        }
    }
    __syncthreads();

    // ---- combine waves + sparse, write y (shape (1,10,M) -> y[b*M + m]) ----
    if (t < RB * BQ) {
        const int r = t / BQ;
        const int b = t % BQ;
        float v = lds_sp[r][b];
        #pragma unroll
        for (int w = 0; w < NTHREADS / 64; ++w)
            v += lds_part[w][r * BQ + b];
        y[b * M_DIM + (m0 + r)] = v;
    }
}

extern "C" void kernel_launch(void* const* d_in, const int* in_sizes, int n_in,
                              void* d_out, int out_size, void* d_ws, size_t ws_size,
                              hipStream_t stream)
{
    const float* x    = (const float*)d_in[0];
    const int*   W    = (const int*)  d_in[1];
    const int*   Ws   = (const int*)  d_in[2];
    const int*   Wz   = (const int*)  d_in[3];
    const float* Wss  = (const float*)d_in[4];
    const float* Wsz  = (const float*)d_in[5];
    const float* Wzs  = (const float*)d_in[6];
    const float* Wzz  = (const float*)d_in[7];
    const int*   roff = (const int*)  d_in[8];
    const int*   cids = (const int*)  d_in[9];
    const float* vals = (const float*)d_in[10];
    float* yout = (float*)d_out;

    dim3 grid(M_DIM / RB);
    dim3 block(NTHREADS);
    spqr_fused<<<grid, block, 0, stream>>>(x, W, Ws, Wz, Wss, Wsz, Wzs, Wzz,
                                           roff, cids, vals, yout);
}